// Round 4
// baseline (322.306 us; speedup 1.0000x reference)
//
#include <hip/hip_runtime.h>
#include <hip/hip_bf16.h>

#define SQL 2048
#define SKL 2048
#define HH  1024
#define NHH 16
#define HDD 64
#define BB  2
#define MM  (BB*SQL)   // 4096 tokens

typedef __attribute__((ext_vector_type(8))) short short8;
typedef __attribute__((ext_vector_type(4))) short short4v;
typedef __attribute__((ext_vector_type(4))) float f32x4;
typedef unsigned short u16;

__device__ inline u16 f2bf(float f) {
    unsigned int u = __float_as_uint(f);
    u += 0x7fffu + ((u >> 16) & 1u);   // RNE
    return (u16)(u >> 16);
}

__device__ inline void gl_lds16(const void* g, void* l) {
    __builtin_amdgcn_global_load_lds(
        (const __attribute__((address_space(1))) unsigned int*)g,
        (__attribute__((address_space(3))) unsigned int*)l, 16, 0, 0);
}

// ---------------- weights fp32 -> bf16 (x-inputs converted in-GEMM) ----------------
__global__ __launch_bounds__(256) void cvt_w_kernel(
    const float* __restrict__ wq, const float* __restrict__ wk,
    const float* __restrict__ wv, const float* __restrict__ wo,
    u16* __restrict__ wqb, u16* __restrict__ wkb, u16* __restrict__ wvb, u16* __restrict__ wob)
{
    int b = blockIdx.x;
    const float* src; u16* dst;
    if      (b < 1024) { src = wq; dst = wqb; }
    else if (b < 2048) { src = wk; dst = wkb; b -= 1024; }
    else if (b < 3072) { src = wv; dst = wvb; b -= 2048; }
    else               { src = wo; dst = wob; b -= 3072; }
    int i = (b * 256 + threadIdx.x) * 4;
    float4 vv = *(const float4*)(src + i);
    ushort4 oo;
    oo.x = f2bf(vv.x); oo.y = f2bf(vv.y); oo.z = f2bf(vv.z); oo.w = f2bf(vv.w);
    *(ushort4*)(dst + i) = oo;
}

// ---------------- fused QKV projection GEMM ----------------
// A (fp32, converted during staging): z=0 query, z=1 key, z=2 value. W bf16.
// 128x128 tile, BK=32, xor-swizzled LDS (chunk ^ ((row>>1)&3)).
// z<2 epilogue -> bf16 [b][head][s][d] (z=0 scaled 0.125*log2e).
// z==2: swapped MFMA operands -> V^T bf16 [b][head][d][s].
__global__ __launch_bounds__(256) void qkv_gemm_kernel(
    const float* __restrict__ xq, const float* __restrict__ xk, const float* __restrict__ xv,
    const u16* __restrict__ wqb, const u16* __restrict__ wkb, const u16* __restrict__ wvb,
    const float* __restrict__ bq, const float* __restrict__ bk, const float* __restrict__ bv,
    u16* __restrict__ oq, u16* __restrict__ ok, u16* __restrict__ ov)
{
    const int z = blockIdx.z;
    const float* A = (z == 0) ? xq : (z == 1) ? xk : xv;
    const u16* W = (z == 0) ? wqb : (z == 1) ? wkb : wvb;
    const float* bias = (z == 0) ? bq : (z == 1) ? bk : bv;
    u16* outb = (z == 0) ? oq : (z == 1) ? ok : ov;
    const float scale = (z == 0) ? 0.125f * 1.4426950408889634f : 1.0f;

    __shared__ u16 lds_a[128 * 32];
    __shared__ u16 lds_b[128 * 32];

    const int t = threadIdx.x;
    const int lane = t & 63;
    const int quad = lane >> 4;
    const int lo = lane & 15;
    const int wv_ = t >> 6;
    const int wm = (wv_ >> 1) * 64, wn = (wv_ & 1) * 64;
    const int m0 = blockIdx.x * 128;
    const int n0 = blockIdx.y * 128;

    f32x4 acc[4][4];
#pragma unroll
    for (int i = 0; i < 4; i++)
#pragma unroll
        for (int j = 0; j < 4; j++) acc[i][j] = (f32x4){0.f, 0.f, 0.f, 0.f};

    const int sl0 = t, sl1 = 256 + t;
    const int r0 = sl0 >> 2, c0 = ((sl0 & 3) ^ ((r0 >> 1) & 3)) * 8;
    const int r1 = sl1 >> 2, c1 = ((sl1 & 3) ^ ((r1 >> 1) & 3)) * 8;
    const float* arow0 = A + (size_t)(m0 + r0) * HH + c0;
    const float* arow1 = A + (size_t)(m0 + r1) * HH + c1;

    for (int k0 = 0; k0 < HH; k0 += 32) {
        // A: fp32 -> bf16 convert in regs, swizzled ds_write_b128
        {
            float4 f0 = *(const float4*)(arow0 + k0);
            float4 f1 = *(const float4*)(arow0 + k0 + 4);
            float4 f2 = *(const float4*)(arow1 + k0);
            float4 f3 = *(const float4*)(arow1 + k0 + 4);
            short8 h0, h1;
            h0[0] = (short)f2bf(f0.x); h0[1] = (short)f2bf(f0.y);
            h0[2] = (short)f2bf(f0.z); h0[3] = (short)f2bf(f0.w);
            h0[4] = (short)f2bf(f1.x); h0[5] = (short)f2bf(f1.y);
            h0[6] = (short)f2bf(f1.z); h0[7] = (short)f2bf(f1.w);
            h1[0] = (short)f2bf(f2.x); h1[1] = (short)f2bf(f2.y);
            h1[2] = (short)f2bf(f2.z); h1[3] = (short)f2bf(f2.w);
            h1[4] = (short)f2bf(f3.x); h1[5] = (short)f2bf(f3.y);
            h1[6] = (short)f2bf(f3.z); h1[7] = (short)f2bf(f3.w);
            *(short8*)&lds_a[sl0 * 8] = h0;
            *(short8*)&lds_a[sl1 * 8] = h1;
        }
        gl_lds16(W + (size_t)(n0 + r0) * HH + k0 + c0, &lds_b[sl0 * 8]);
        gl_lds16(W + (size_t)(n0 + r1) * HH + k0 + c1, &lds_b[sl1 * 8]);
        __syncthreads();
        short8 af[4], bf[4];
#pragma unroll
        for (int i = 0; i < 4; i++) {
            const int ra = wm + i * 16 + lo;
            const int rb = wn + i * 16 + lo;
            af[i] = *(const short8*)&lds_a[ra * 32 + ((quad ^ ((ra >> 1) & 3)) * 8)];
            bf[i] = *(const short8*)&lds_b[rb * 32 + ((quad ^ ((rb >> 1) & 3)) * 8)];
        }
        if (z == 2) {
#pragma unroll
            for (int i = 0; i < 4; i++)
#pragma unroll
                for (int j = 0; j < 4; j++)
                    acc[i][j] = __builtin_amdgcn_mfma_f32_16x16x32_bf16(bf[j], af[i], acc[i][j], 0, 0, 0);
        } else {
#pragma unroll
            for (int i = 0; i < 4; i++)
#pragma unroll
                for (int j = 0; j < 4; j++)
                    acc[i][j] = __builtin_amdgcn_mfma_f32_16x16x32_bf16(af[i], bf[j], acc[i][j], 0, 0, 0);
        }
        __syncthreads();
    }

#pragma unroll
    for (int i = 0; i < 4; i++) {
#pragma unroll
        for (int j = 0; j < 4; j++) {
#pragma unroll
            for (int r = 0; r < 4; r++) {
                if (z == 2) {
                    int dg  = n0 + wn + j * 16 + quad * 4 + r;   // weight dim
                    int tok = m0 + wm + i * 16 + lo;
                    float val = acc[i][j][r] + bias[dg];
                    int head = dg >> 6, d = dg & 63;
                    int bi = tok >> 11, s = tok & 2047;
                    outb[(((size_t)bi * NHH + head) * HDD + d) * SKL + s] = f2bf(val);
                } else {
                    int row = m0 + wm + i * 16 + quad * 4 + r;   // token
                    int col = n0 + wn + j * 16 + lo;
                    float val = (acc[i][j][r] + bias[col]) * scale;
                    int bi = row >> 11, s = row & 2047;
                    int head = col >> 6, d = col & 63;
                    outb[(((size_t)bi * NHH + head) * SQL + s) * HDD + d] = f2bf(val);
                }
            }
        }
    }
}

// ---------------- out-projection GEMM, split-K=2 ----------------
__global__ __launch_bounds__(256) void oproj_kernel(
    const u16* __restrict__ A, const u16* __restrict__ W,
    const float* __restrict__ bias, const float* __restrict__ resid,
    float* __restrict__ p0, float* __restrict__ p1)
{
    const int z = blockIdx.z;
    float* outf = z ? p1 : p0;

    __shared__ u16 lds_a[128 * 32];
    __shared__ u16 lds_b[128 * 32];

    const int t = threadIdx.x;
    const int lane = t & 63;
    const int quad = lane >> 4;
    const int lo = lane & 15;
    const int wv_ = t >> 6;
    const int wm = (wv_ >> 1) * 64, wn = (wv_ & 1) * 64;
    const int m0 = blockIdx.x * 128;
    const int n0 = blockIdx.y * 128;

    f32x4 acc[4][4];
#pragma unroll
    for (int i = 0; i < 4; i++)
#pragma unroll
        for (int j = 0; j < 4; j++) acc[i][j] = (f32x4){0.f, 0.f, 0.f, 0.f};

    const int sl0 = t, sl1 = 256 + t;
    const int r0 = sl0 >> 2, c0 = ((sl0 & 3) ^ ((r0 >> 1) & 3)) * 8;
    const int r1 = sl1 >> 2, c1 = ((sl1 & 3) ^ ((r1 >> 1) & 3)) * 8;

    const int kbeg = z * 512, kend = kbeg + 512;
    for (int k0 = kbeg; k0 < kend; k0 += 32) {
        gl_lds16(A + (size_t)(m0 + r0) * HH + k0 + c0, &lds_a[sl0 * 8]);
        gl_lds16(A + (size_t)(m0 + r1) * HH + k0 + c1, &lds_a[sl1 * 8]);
        gl_lds16(W + (size_t)(n0 + r0) * HH + k0 + c0, &lds_b[sl0 * 8]);
        gl_lds16(W + (size_t)(n0 + r1) * HH + k0 + c1, &lds_b[sl1 * 8]);
        __syncthreads();
        short8 af[4], bf[4];
#pragma unroll
        for (int i = 0; i < 4; i++) {
            const int ra = wm + i * 16 + lo;
            const int rb = wn + i * 16 + lo;
            af[i] = *(const short8*)&lds_a[ra * 32 + ((quad ^ ((ra >> 1) & 3)) * 8)];
            bf[i] = *(const short8*)&lds_b[rb * 32 + ((quad ^ ((rb >> 1) & 3)) * 8)];
        }
#pragma unroll
        for (int i = 0; i < 4; i++)
#pragma unroll
            for (int j = 0; j < 4; j++)
                acc[i][j] = __builtin_amdgcn_mfma_f32_16x16x32_bf16(af[i], bf[j], acc[i][j], 0, 0, 0);
        __syncthreads();
    }

#pragma unroll
    for (int i = 0; i < 4; i++) {
#pragma unroll
        for (int j = 0; j < 4; j++) {
#pragma unroll
            for (int r = 0; r < 4; r++) {
                int row = m0 + wm + i * 16 + quad * 4 + r;
                int col = n0 + wn + j * 16 + lo;
                float val = acc[i][j][r];
                if (z == 0) val += bias[col] + resid[(size_t)row * HH + col];
                outf[(size_t)row * HH + col] = val;
            }
        }
    }
}

// ---------------- Flash attention (verbatim R2: 64-key tiles, S^T orientation) ----------------
#define PSTR 72   // [16 q][64 key] P tile row stride (u16)

__global__ __launch_bounds__(256) void attn_kernel(
    const u16* __restrict__ qb, const u16* __restrict__ kb, const u16* __restrict__ vtb,
    u16* __restrict__ attn_out)
{
    __shared__ u16 k_lds[64 * 64];
    __shared__ u16 vt_lds[64 * 64];
    __shared__ u16 p_lds[4 * 16 * PSTR];

    const int t = threadIdx.x;
    const int lane = t & 63;
    const int quad = lane >> 4;
    const int lo = lane & 15;
    const int w = t >> 6;
    const int qt = (SQL / 64 - 1) - (blockIdx.x >> 5);  // heavy q-tiles first
    const int bh = blockIdx.x & 31;
    const int q0 = qt * 64;

    const u16* qbase = qb + ((size_t)bh * SQL + q0 + w * 16 + lo) * HDD + quad * 8;
    short8 qf0 = *(const short8*)qbase;
    short8 qf1 = *(const short8*)(qbase + 32);

    float m_s = -__builtin_inff(), l_s = 0.f;   // per q = lane&15 (replicated per quad)
    f32x4 o[4];
#pragma unroll
    for (int j = 0; j < 4; j++) o[j] = (f32x4){0.f, 0.f, 0.f, 0.f};

    const int sl0 = t, sl1 = 256 + t;
    const int r0 = sl0 >> 3, c0 = ((sl0 & 7) ^ (r0 & 7)) * 8;
    const int r1 = sl1 >> 3, c1 = ((sl1 & 7) ^ (r1 & 7)) * 8;
    const u16* kbh = kb + (size_t)bh * SKL * HDD;
    const u16* vbh = vtb + (size_t)bh * HDD * SKL;
    u16* ppriv = &p_lds[w * 16 * PSTR];

    for (int kt = 0; kt <= qt; kt++) {
        const int k0 = kt * 64;
        gl_lds16(kbh + (size_t)(k0 + r0) * HDD + c0, &k_lds[sl0 * 8]);
        gl_lds16(kbh + (size_t)(k0 + r1) * HDD + c1, &k_lds[sl1 * 8]);
        gl_lds16(vbh + (size_t)r0 * SKL + k0 + c0, &vt_lds[sl0 * 8]);
        gl_lds16(vbh + (size_t)r1 * SKL + k0 + c1, &vt_lds[sl1 * 8]);
        __syncthreads();

        // S^T = K·Q^T : A-frag = K rows, B-frag = Q rows
        f32x4 s[4];
#pragma unroll
        for (int nt = 0; nt < 4; nt++) {
            const int row = nt * 16 + lo;
            short8 kf0 = *(const short8*)&k_lds[row * 64 + ((quad ^ (row & 7)) * 8)];
            short8 kf1 = *(const short8*)&k_lds[row * 64 + (((4 + quad) ^ (row & 7)) * 8)];
            s[nt] = (f32x4){0.f, 0.f, 0.f, 0.f};
            s[nt] = __builtin_amdgcn_mfma_f32_16x16x32_bf16(kf0, qf0, s[nt], 0, 0, 0);
            s[nt] = __builtin_amdgcn_mfma_f32_16x16x32_bf16(kf1, qf1, s[nt], 0, 0, 0);
        }
        if (kt == qt) {   // diagonal tile: mask key > q
            const int ql = w * 16 + lo;
#pragma unroll
            for (int nt = 0; nt < 4; nt++)
#pragma unroll
                for (int r = 0; r < 4; r++)
                    if (nt * 16 + quad * 4 + r > ql) s[nt][r] = -__builtin_inff();
        }

        // online softmax (log2 domain)
        float mx = s[0][0];
#pragma unroll
        for (int nt = 0; nt < 4; nt++)
#pragma unroll
            for (int r = 0; r < 4; r++) mx = fmaxf(mx, s[nt][r]);
        mx = fmaxf(mx, __shfl_xor(mx, 16));
        mx = fmaxf(mx, __shfl_xor(mx, 32));
        float mnew = fmaxf(m_s, mx);
        float al = __builtin_amdgcn_exp2f(m_s - mnew);
        m_s = mnew;
        float rs = 0.f;
#pragma unroll
        for (int nt = 0; nt < 4; nt++)
#pragma unroll
            for (int r = 0; r < 4; r++) {
                s[nt][r] = __builtin_amdgcn_exp2f(s[nt][r] - m_s);
                rs += s[nt][r];
            }
        rs += __shfl_xor(rs, 16);
        rs += __shfl_xor(rs, 32);
        l_s = l_s * al + rs;

        float alr[4];
#pragma unroll
        for (int r = 0; r < 4; r++) alr[r] = __shfl(al, quad * 4 + r, 16);
#pragma unroll
        for (int nt = 0; nt < 4; nt++)
#pragma unroll
            for (int r = 0; r < 4; r++) o[nt][r] *= alr[r];

        // P store: 4 consecutive keys per lane, b64 writes
#pragma unroll
        for (int nt = 0; nt < 4; nt++) {
            short4v pk;
#pragma unroll
            for (int r = 0; r < 4; r++) pk[r] = (short)f2bf(s[nt][r]);
            *(short4v*)&ppriv[lo * PSTR + nt * 16 + quad * 4] = pk;
        }
        short8 pf0 = *(const short8*)&ppriv[lo * PSTR + quad * 8];
        short8 pf1 = *(const short8*)&ppriv[lo * PSTR + 32 + quad * 8];

        // O += P·V : B-frag = V^T rows
#pragma unroll
        for (int nt = 0; nt < 4; nt++) {
            const int row = nt * 16 + lo;
            short8 vf0 = *(const short8*)&vt_lds[row * 64 + ((quad ^ (row & 7)) * 8)];
            short8 vf1 = *(const short8*)&vt_lds[row * 64 + (((4 + quad) ^ (row & 7)) * 8)];
            o[nt] = __builtin_amdgcn_mfma_f32_16x16x32_bf16(pf0, vf0, o[nt], 0, 0, 0);
            o[nt] = __builtin_amdgcn_mfma_f32_16x16x32_bf16(pf1, vf1, o[nt], 0, 0, 0);
        }
        __syncthreads();
    }

    // epilogue
    const int b = bh >> 4, h = bh & 15;
    float inv[4];
#pragma unroll
    for (int r = 0; r < 4; r++) inv[r] = 1.0f / __shfl(l_s, quad * 4 + r, 16);
#pragma unroll
    for (int nt = 0; nt < 4; nt++)
#pragma unroll
        for (int r = 0; r < 4; r++) {
            int srow = q0 + w * 16 + quad * 4 + r;
            attn_out[((size_t)b * SQL + srow) * HH + h * HDD + nt * 16 + lo] =
                f2bf(o[nt][r] * inv[r]);
        }
}

// ---------------- LayerNorm over split-K partials ----------------
__global__ __launch_bounds__(256) void ln_kernel(const float* __restrict__ p0,
                                                 const float* __restrict__ p1,
                                                 const float* __restrict__ g,
                                                 const float* __restrict__ bb,
                                                 float* __restrict__ out)
{
    const int row = blockIdx.x;
    const int t = threadIdx.x;
    float4 a = *(const float4*)(p0 + (size_t)row * HH + t * 4);
    float4 c = *(const float4*)(p1 + (size_t)row * HH + t * 4);
    float4 v;
    v.x = a.x + c.x; v.y = a.y + c.y; v.z = a.z + c.z; v.w = a.w + c.w;
    float s1 = v.x + v.y + v.z + v.w;
    float s2 = v.x * v.x + v.y * v.y + v.z * v.z + v.w * v.w;
#pragma unroll
    for (int off = 32; off; off >>= 1) { s1 += __shfl_xor(s1, off); s2 += __shfl_xor(s2, off); }
    __shared__ float red[8];
    if ((t & 63) == 0) { red[(t >> 6) * 2] = s1; red[(t >> 6) * 2 + 1] = s2; }
    __syncthreads();
    s1 = red[0] + red[2] + red[4] + red[6];
    s2 = red[1] + red[3] + red[5] + red[7];
    float mu = s1 * (1.0f / HH);
    float var = s2 * (1.0f / HH) - mu * mu;
    float rstd = rsqrtf(var + 1e-5f);
    float4 gg = *(const float4*)(g + t * 4);
    float4 b4 = *(const float4*)(bb + t * 4);
    float4 o;
    o.x = (v.x - mu) * rstd * gg.x + b4.x;
    o.y = (v.y - mu) * rstd * gg.y + b4.y;
    o.z = (v.z - mu) * rstd * gg.z + b4.z;
    o.w = (v.w - mu) * rstd * gg.w + b4.w;
    *(float4*)(out + (size_t)row * HH + t * 4) = o;
}

extern "C" void kernel_launch(void* const* d_in, const int* in_sizes, int n_in,
                              void* d_out, int out_size, void* d_ws, size_t ws_size,
                              hipStream_t stream)
{
    const float* query = (const float*)d_in[0];
    const float* key   = (const float*)d_in[1];
    const float* value = (const float*)d_in[2];
    // d_in[3] = causal_mask (tril by construction; causality hardcoded)
    const float* Wq = (const float*)d_in[4];
    const float* bq = (const float*)d_in[5];
    const float* Wk = (const float*)d_in[6];
    const float* bk = (const float*)d_in[7];
    const float* Wv = (const float*)d_in[8];
    const float* bv = (const float*)d_in[9];
    const float* Wo = (const float*)d_in[10];
    const float* bo = (const float*)d_in[11];
    const float* ln_g = (const float*)d_in[12];
    const float* ln_b = (const float*)d_in[13];
    float* out = (float*)d_out;

    char* wp = (char*)d_ws;
    auto alloc = [&](size_t bytes) { void* p = (void*)wp; wp += (bytes + 255) & ~(size_t)255; return p; };
    const int nW = HH * HH;    // 1M
    const int nX = MM * HH;    // 4M
    u16* wqb = (u16*)alloc((size_t)nW * 2);
    u16* wkb = (u16*)alloc((size_t)nW * 2);
    u16* wvb = (u16*)alloc((size_t)nW * 2);
    u16* wob = (u16*)alloc((size_t)nW * 2);
    u16* qbuf = (u16*)alloc((size_t)nX * 2);   // [b][h][s][d]
    u16* kbuf = (u16*)alloc((size_t)nX * 2);   // [b][h][s][d]
    u16* vbuf = (u16*)alloc((size_t)nX * 2);   // V^T [b][h][d][s]
    u16* attnb = (u16*)alloc((size_t)nX * 2);  // [b][s][h*d]
    float* p0 = (float*)alloc((size_t)nX * 4);
    float* p1 = (float*)alloc((size_t)nX * 4);

    cvt_w_kernel<<<4096, 256, 0, stream>>>(Wq, Wk, Wv, Wo, wqb, wkb, wvb, wob);

    qkv_gemm_kernel<<<dim3(32, 8, 3), 256, 0, stream>>>(
        query, key, value, wqb, wkb, wvb, bq, bk, bv, qbuf, kbuf, vbuf);

    attn_kernel<<<1024, 256, 0, stream>>>(qbuf, kbuf, vbuf, attnb);

    oproj_kernel<<<dim3(32, 8, 2), 256, 0, stream>>>(attnb, wob, bo, query, p0, p1);

    ln_kernel<<<MM, 256, 0, stream>>>(p0, p1, ln_g, ln_b, out);
}

// Round 5
// 288.317 us; speedup vs baseline: 1.1179x; 1.1179x over previous
//
#include <hip/hip_runtime.h>
#include <hip/hip_bf16.h>

#define SQL 2048
#define SKL 2048
#define HH  1024
#define NHH 16
#define HDD 64
#define BB  2
#define MM  (BB*SQL)   // 4096 tokens

typedef __attribute__((ext_vector_type(8))) short short8;
typedef __attribute__((ext_vector_type(4))) short short4v;
typedef __attribute__((ext_vector_type(4))) float f32x4;
typedef unsigned short u16;

__device__ inline u16 f2bf(float f) {
    unsigned int u = __float_as_uint(f);
    u += 0x7fffu + ((u >> 16) & 1u);   // RNE
    return (u16)(u >> 16);
}

__device__ inline void gl_lds16(const void* g, void* l) {
    __builtin_amdgcn_global_load_lds(
        (const __attribute__((address_space(1))) unsigned int*)g,
        (__attribute__((address_space(3))) unsigned int*)l, 16, 0, 0);
}

// ---------------- fused fp32 -> bf16 convert (3 inputs + 4 weights, 1 launch) ----------------
__global__ __launch_bounds__(256) void cvt_all_kernel(
    const float* __restrict__ q, const float* __restrict__ k, const float* __restrict__ v,
    const float* __restrict__ wq, const float* __restrict__ wk,
    const float* __restrict__ wv, const float* __restrict__ wo,
    u16* __restrict__ xq, u16* __restrict__ xk, u16* __restrict__ xv,
    u16* __restrict__ wqb, u16* __restrict__ wkb, u16* __restrict__ wvb, u16* __restrict__ wob)
{
    int b = blockIdx.x;
    const float* src; u16* dst;
    if      (b < 4096)  { src = q;  dst = xq; }
    else if (b < 8192)  { src = k;  dst = xk;  b -= 4096; }
    else if (b < 12288) { src = v;  dst = xv;  b -= 8192; }
    else if (b < 13312) { src = wq; dst = wqb; b -= 12288; }
    else if (b < 14336) { src = wk; dst = wkb; b -= 13312; }
    else if (b < 15360) { src = wv; dst = wvb; b -= 14336; }
    else                { src = wo; dst = wob; b -= 15360; }
    int i = (b * 256 + threadIdx.x) * 4;
    float4 vv = *(const float4*)(src + i);
    ushort4 oo;
    oo.x = f2bf(vv.x); oo.y = f2bf(vv.y); oo.z = f2bf(vv.z); oo.w = f2bf(vv.w);
    *(ushort4*)(dst + i) = oo;
}

// ---------------- fused QKV projection GEMM (bf16 A, async staging) ----------------
// A bf16 [4096][1024]; W bf16 [1024][1024]. 128x128 tile, BK=32, xor-swizzled LDS.
// z=0: Q -> [b][h][s][d] scaled 0.125*log2e; z=1: K -> [b][h][s][d];
// z=2: swapped MFMA operands -> V^T [b][h][d][s].
__global__ __launch_bounds__(256) void qkv_gemm_kernel(
    const u16* __restrict__ xq, const u16* __restrict__ xk, const u16* __restrict__ xv,
    const u16* __restrict__ wqb, const u16* __restrict__ wkb, const u16* __restrict__ wvb,
    const float* __restrict__ bq, const float* __restrict__ bk, const float* __restrict__ bv,
    u16* __restrict__ oq, u16* __restrict__ ok, u16* __restrict__ ov)
{
    const int z = blockIdx.z;
    const u16* A = (z == 0) ? xq : (z == 1) ? xk : xv;
    const u16* W = (z == 0) ? wqb : (z == 1) ? wkb : wvb;
    const float* bias = (z == 0) ? bq : (z == 1) ? bk : bv;
    u16* outb = (z == 0) ? oq : (z == 1) ? ok : ov;
    const float scale = (z == 0) ? 0.125f * 1.4426950408889634f : 1.0f;

    __shared__ u16 lds_a[128 * 32];
    __shared__ u16 lds_b[128 * 32];

    const int t = threadIdx.x;
    const int lane = t & 63;
    const int quad = lane >> 4;
    const int lo = lane & 15;
    const int wv_ = t >> 6;
    const int wm = (wv_ >> 1) * 64, wn = (wv_ & 1) * 64;
    const int m0 = blockIdx.x * 128;
    const int n0 = blockIdx.y * 128;

    f32x4 acc[4][4];
#pragma unroll
    for (int i = 0; i < 4; i++)
#pragma unroll
        for (int j = 0; j < 4; j++) acc[i][j] = (f32x4){0.f, 0.f, 0.f, 0.f};

    const int sl0 = t, sl1 = 256 + t;
    const int r0 = sl0 >> 2, c0 = ((sl0 & 3) ^ ((r0 >> 1) & 3)) * 8;
    const int r1 = sl1 >> 2, c1 = ((sl1 & 3) ^ ((r1 >> 1) & 3)) * 8;

    for (int k0 = 0; k0 < HH; k0 += 32) {
        gl_lds16(A + (size_t)(m0 + r0) * HH + k0 + c0, &lds_a[sl0 * 8]);
        gl_lds16(A + (size_t)(m0 + r1) * HH + k0 + c1, &lds_a[sl1 * 8]);
        gl_lds16(W + (size_t)(n0 + r0) * HH + k0 + c0, &lds_b[sl0 * 8]);
        gl_lds16(W + (size_t)(n0 + r1) * HH + k0 + c1, &lds_b[sl1 * 8]);
        __syncthreads();
        short8 af[4], bf[4];
#pragma unroll
        for (int i = 0; i < 4; i++) {
            const int ra = wm + i * 16 + lo;
            const int rb = wn + i * 16 + lo;
            af[i] = *(const short8*)&lds_a[ra * 32 + ((quad ^ ((ra >> 1) & 3)) * 8)];
            bf[i] = *(const short8*)&lds_b[rb * 32 + ((quad ^ ((rb >> 1) & 3)) * 8)];
        }
        if (z == 2) {
#pragma unroll
            for (int i = 0; i < 4; i++)
#pragma unroll
                for (int j = 0; j < 4; j++)
                    acc[i][j] = __builtin_amdgcn_mfma_f32_16x16x32_bf16(bf[j], af[i], acc[i][j], 0, 0, 0);
        } else {
#pragma unroll
            for (int i = 0; i < 4; i++)
#pragma unroll
                for (int j = 0; j < 4; j++)
                    acc[i][j] = __builtin_amdgcn_mfma_f32_16x16x32_bf16(af[i], bf[j], acc[i][j], 0, 0, 0);
        }
        __syncthreads();
    }

#pragma unroll
    for (int i = 0; i < 4; i++) {
#pragma unroll
        for (int j = 0; j < 4; j++) {
#pragma unroll
            for (int r = 0; r < 4; r++) {
                if (z == 2) {
                    int dg  = n0 + wn + j * 16 + quad * 4 + r;   // weight dim
                    int tok = m0 + wm + i * 16 + lo;
                    float val = acc[i][j][r] + bias[dg];
                    int head = dg >> 6, d = dg & 63;
                    int bi = tok >> 11, s = tok & 2047;
                    outb[(((size_t)bi * NHH + head) * HDD + d) * SKL + s] = f2bf(val);
                } else {
                    int row = m0 + wm + i * 16 + quad * 4 + r;   // token
                    int col = n0 + wn + j * 16 + lo;
                    float val = (acc[i][j][r] + bias[col]) * scale;
                    int bi = row >> 11, s = row & 2047;
                    int head = col >> 6, d = col & 63;
                    outb[(((size_t)bi * NHH + head) * SQL + s) * HDD + d] = f2bf(val);
                }
            }
        }
    }
}

// ---------------- out-projection GEMM, split-K=2 ----------------
__global__ __launch_bounds__(256) void oproj_kernel(
    const u16* __restrict__ A, const u16* __restrict__ W,
    const float* __restrict__ bias, const float* __restrict__ resid,
    float* __restrict__ p0, float* __restrict__ p1)
{
    const int z = blockIdx.z;
    float* outf = z ? p1 : p0;

    __shared__ u16 lds_a[128 * 32];
    __shared__ u16 lds_b[128 * 32];

    const int t = threadIdx.x;
    const int lane = t & 63;
    const int quad = lane >> 4;
    const int lo = lane & 15;
    const int wv_ = t >> 6;
    const int wm = (wv_ >> 1) * 64, wn = (wv_ & 1) * 64;
    const int m0 = blockIdx.x * 128;
    const int n0 = blockIdx.y * 128;

    f32x4 acc[4][4];
#pragma unroll
    for (int i = 0; i < 4; i++)
#pragma unroll
        for (int j = 0; j < 4; j++) acc[i][j] = (f32x4){0.f, 0.f, 0.f, 0.f};

    const int sl0 = t, sl1 = 256 + t;
    const int r0 = sl0 >> 2, c0 = ((sl0 & 3) ^ ((r0 >> 1) & 3)) * 8;
    const int r1 = sl1 >> 2, c1 = ((sl1 & 3) ^ ((r1 >> 1) & 3)) * 8;

    const int kbeg = z * 512, kend = kbeg + 512;
    for (int k0 = kbeg; k0 < kend; k0 += 32) {
        gl_lds16(A + (size_t)(m0 + r0) * HH + k0 + c0, &lds_a[sl0 * 8]);
        gl_lds16(A + (size_t)(m0 + r1) * HH + k0 + c1, &lds_a[sl1 * 8]);
        gl_lds16(W + (size_t)(n0 + r0) * HH + k0 + c0, &lds_b[sl0 * 8]);
        gl_lds16(W + (size_t)(n0 + r1) * HH + k0 + c1, &lds_b[sl1 * 8]);
        __syncthreads();
        short8 af[4], bf[4];
#pragma unroll
        for (int i = 0; i < 4; i++) {
            const int ra = wm + i * 16 + lo;
            const int rb = wn + i * 16 + lo;
            af[i] = *(const short8*)&lds_a[ra * 32 + ((quad ^ ((ra >> 1) & 3)) * 8)];
            bf[i] = *(const short8*)&lds_b[rb * 32 + ((quad ^ ((rb >> 1) & 3)) * 8)];
        }
#pragma unroll
        for (int i = 0; i < 4; i++)
#pragma unroll
            for (int j = 0; j < 4; j++)
                acc[i][j] = __builtin_amdgcn_mfma_f32_16x16x32_bf16(af[i], bf[j], acc[i][j], 0, 0, 0);
        __syncthreads();
    }

#pragma unroll
    for (int i = 0; i < 4; i++) {
#pragma unroll
        for (int j = 0; j < 4; j++) {
#pragma unroll
            for (int r = 0; r < 4; r++) {
                int row = m0 + wm + i * 16 + quad * 4 + r;
                int col = n0 + wn + j * 16 + lo;
                float val = acc[i][j][r];
                if (z == 0) val += bias[col] + resid[(size_t)row * HH + col];
                outf[(size_t)row * HH + col] = val;
            }
        }
    }
}

// ---------------- Flash attention (R2-verbatim: 64-key tiles, S^T orientation) ----------------
#define PSTR 72   // [16 q][64 key] P tile row stride (u16)

__global__ __launch_bounds__(256) void attn_kernel(
    const u16* __restrict__ qb, const u16* __restrict__ kb, const u16* __restrict__ vtb,
    u16* __restrict__ attn_out)
{
    __shared__ u16 k_lds[64 * 64];
    __shared__ u16 vt_lds[64 * 64];
    __shared__ u16 p_lds[4 * 16 * PSTR];

    const int t = threadIdx.x;
    const int lane = t & 63;
    const int quad = lane >> 4;
    const int lo = lane & 15;
    const int w = t >> 6;
    const int qt = (SQL / 64 - 1) - (blockIdx.x >> 5);  // heavy q-tiles first
    const int bh = blockIdx.x & 31;
    const int q0 = qt * 64;

    const u16* qbase = qb + ((size_t)bh * SQL + q0 + w * 16 + lo) * HDD + quad * 8;
    short8 qf0 = *(const short8*)qbase;
    short8 qf1 = *(const short8*)(qbase + 32);

    float m_s = -__builtin_inff(), l_s = 0.f;   // per q = lane&15 (replicated per quad)
    f32x4 o[4];
#pragma unroll
    for (int j = 0; j < 4; j++) o[j] = (f32x4){0.f, 0.f, 0.f, 0.f};

    const int sl0 = t, sl1 = 256 + t;
    const int r0 = sl0 >> 3, c0 = ((sl0 & 7) ^ (r0 & 7)) * 8;
    const int r1 = sl1 >> 3, c1 = ((sl1 & 7) ^ (r1 & 7)) * 8;
    const u16* kbh = kb + (size_t)bh * SKL * HDD;
    const u16* vbh = vtb + (size_t)bh * HDD * SKL;
    u16* ppriv = &p_lds[w * 16 * PSTR];

    for (int kt = 0; kt <= qt; kt++) {
        const int k0 = kt * 64;
        gl_lds16(kbh + (size_t)(k0 + r0) * HDD + c0, &k_lds[sl0 * 8]);
        gl_lds16(kbh + (size_t)(k0 + r1) * HDD + c1, &k_lds[sl1 * 8]);
        gl_lds16(vbh + (size_t)r0 * SKL + k0 + c0, &vt_lds[sl0 * 8]);
        gl_lds16(vbh + (size_t)r1 * SKL + k0 + c1, &vt_lds[sl1 * 8]);
        __syncthreads();

        // S^T = K·Q^T
        f32x4 s[4];
#pragma unroll
        for (int nt = 0; nt < 4; nt++) {
            const int row = nt * 16 + lo;
            short8 kf0 = *(const short8*)&k_lds[row * 64 + ((quad ^ (row & 7)) * 8)];
            short8 kf1 = *(const short8*)&k_lds[row * 64 + (((4 + quad) ^ (row & 7)) * 8)];
            s[nt] = (f32x4){0.f, 0.f, 0.f, 0.f};
            s[nt] = __builtin_amdgcn_mfma_f32_16x16x32_bf16(kf0, qf0, s[nt], 0, 0, 0);
            s[nt] = __builtin_amdgcn_mfma_f32_16x16x32_bf16(kf1, qf1, s[nt], 0, 0, 0);
        }
        if (kt == qt) {   // diagonal tile: mask key > q
            const int ql = w * 16 + lo;
#pragma unroll
            for (int nt = 0; nt < 4; nt++)
#pragma unroll
                for (int r = 0; r < 4; r++)
                    if (nt * 16 + quad * 4 + r > ql) s[nt][r] = -__builtin_inff();
        }

        // online softmax (log2 domain)
        float mx = s[0][0];
#pragma unroll
        for (int nt = 0; nt < 4; nt++)
#pragma unroll
            for (int r = 0; r < 4; r++) mx = fmaxf(mx, s[nt][r]);
        mx = fmaxf(mx, __shfl_xor(mx, 16));
        mx = fmaxf(mx, __shfl_xor(mx, 32));
        float mnew = fmaxf(m_s, mx);
        float al = __builtin_amdgcn_exp2f(m_s - mnew);
        m_s = mnew;
        float rs = 0.f;
#pragma unroll
        for (int nt = 0; nt < 4; nt++)
#pragma unroll
            for (int r = 0; r < 4; r++) {
                s[nt][r] = __builtin_amdgcn_exp2f(s[nt][r] - m_s);
                rs += s[nt][r];
            }
        rs += __shfl_xor(rs, 16);
        rs += __shfl_xor(rs, 32);
        l_s = l_s * al + rs;

        float alr[4];
#pragma unroll
        for (int r = 0; r < 4; r++) alr[r] = __shfl(al, quad * 4 + r, 16);
#pragma unroll
        for (int nt = 0; nt < 4; nt++)
#pragma unroll
            for (int r = 0; r < 4; r++) o[nt][r] *= alr[r];

        // P store: 4 consecutive keys per lane, b64 writes
#pragma unroll
        for (int nt = 0; nt < 4; nt++) {
            short4v pk;
#pragma unroll
            for (int r = 0; r < 4; r++) pk[r] = (short)f2bf(s[nt][r]);
            *(short4v*)&ppriv[lo * PSTR + nt * 16 + quad * 4] = pk;
        }
        short8 pf0 = *(const short8*)&ppriv[lo * PSTR + quad * 8];
        short8 pf1 = *(const short8*)&ppriv[lo * PSTR + 32 + quad * 8];

        // O += P·V
#pragma unroll
        for (int nt = 0; nt < 4; nt++) {
            const int row = nt * 16 + lo;
            short8 vf0 = *(const short8*)&vt_lds[row * 64 + ((quad ^ (row & 7)) * 8)];
            short8 vf1 = *(const short8*)&vt_lds[row * 64 + (((4 + quad) ^ (row & 7)) * 8)];
            o[nt] = __builtin_amdgcn_mfma_f32_16x16x32_bf16(pf0, vf0, o[nt], 0, 0, 0);
            o[nt] = __builtin_amdgcn_mfma_f32_16x16x32_bf16(pf1, vf1, o[nt], 0, 0, 0);
        }
        __syncthreads();
    }

    // epilogue
    const int b = bh >> 4, h = bh & 15;
    float inv[4];
#pragma unroll
    for (int r = 0; r < 4; r++) inv[r] = 1.0f / __shfl(l_s, quad * 4 + r, 16);
#pragma unroll
    for (int nt = 0; nt < 4; nt++)
#pragma unroll
        for (int r = 0; r < 4; r++) {
            int srow = q0 + w * 16 + quad * 4 + r;
            attn_out[((size_t)b * SQL + srow) * HH + h * HDD + nt * 16 + lo] =
                f2bf(o[nt][r] * inv[r]);
        }
}

// ---------------- LayerNorm over split-K partials ----------------
__global__ __launch_bounds__(256) void ln_kernel(const float* __restrict__ p0,
                                                 const float* __restrict__ p1,
                                                 const float* __restrict__ g,
                                                 const float* __restrict__ bb,
                                                 float* __restrict__ out)
{
    const int row = blockIdx.x;
    const int t = threadIdx.x;
    float4 a = *(const float4*)(p0 + (size_t)row * HH + t * 4);
    float4 c = *(const float4*)(p1 + (size_t)row * HH + t * 4);
    float4 v;
    v.x = a.x + c.x; v.y = a.y + c.y; v.z = a.z + c.z; v.w = a.w + c.w;
    float s1 = v.x + v.y + v.z + v.w;
    float s2 = v.x * v.x + v.y * v.y + v.z * v.z + v.w * v.w;
#pragma unroll
    for (int off = 32; off; off >>= 1) { s1 += __shfl_xor(s1, off); s2 += __shfl_xor(s2, off); }
    __shared__ float red[8];
    if ((t & 63) == 0) { red[(t >> 6) * 2] = s1; red[(t >> 6) * 2 + 1] = s2; }
    __syncthreads();
    s1 = red[0] + red[2] + red[4] + red[6];
    s2 = red[1] + red[3] + red[5] + red[7];
    float mu = s1 * (1.0f / HH);
    float var = s2 * (1.0f / HH) - mu * mu;
    float rstd = rsqrtf(var + 1e-5f);
    float4 gg = *(const float4*)(g + t * 4);
    float4 b4 = *(const float4*)(bb + t * 4);
    float4 o;
    o.x = (v.x - mu) * rstd * gg.x + b4.x;
    o.y = (v.y - mu) * rstd * gg.y + b4.y;
    o.z = (v.z - mu) * rstd * gg.z + b4.z;
    o.w = (v.w - mu) * rstd * gg.w + b4.w;
    *(float4*)(out + (size_t)row * HH + t * 4) = o;
}

extern "C" void kernel_launch(void* const* d_in, const int* in_sizes, int n_in,
                              void* d_out, int out_size, void* d_ws, size_t ws_size,
                              hipStream_t stream)
{
    const float* query = (const float*)d_in[0];
    const float* key   = (const float*)d_in[1];
    const float* value = (const float*)d_in[2];
    // d_in[3] = causal_mask (tril by construction; causality hardcoded)
    const float* Wq = (const float*)d_in[4];
    const float* bq = (const float*)d_in[5];
    const float* Wk = (const float*)d_in[6];
    const float* bk = (const float*)d_in[7];
    const float* Wv = (const float*)d_in[8];
    const float* bv = (const float*)d_in[9];
    const float* Wo = (const float*)d_in[10];
    const float* bo = (const float*)d_in[11];
    const float* ln_g = (const float*)d_in[12];
    const float* ln_b = (const float*)d_in[13];
    float* out = (float*)d_out;

    char* wp = (char*)d_ws;
    auto alloc = [&](size_t bytes) { void* p = (void*)wp; wp += (bytes + 255) & ~(size_t)255; return p; };
    const int nW = HH * HH;    // 1M
    const int nX = MM * HH;    // 4M
    u16* wqb = (u16*)alloc((size_t)nW * 2);
    u16* wkb = (u16*)alloc((size_t)nW * 2);
    u16* wvb = (u16*)alloc((size_t)nW * 2);
    u16* wob = (u16*)alloc((size_t)nW * 2);
    u16* xq  = (u16*)alloc((size_t)nX * 2);
    u16* xk  = (u16*)alloc((size_t)nX * 2);
    u16* xv  = (u16*)alloc((size_t)nX * 2);
    u16* qbuf = (u16*)alloc((size_t)nX * 2);   // [b][h][s][d]
    u16* kbuf = (u16*)alloc((size_t)nX * 2);   // [b][h][s][d]
    u16* vbuf = (u16*)alloc((size_t)nX * 2);   // V^T [b][h][d][s]
    u16* attnb = (u16*)alloc((size_t)nX * 2);  // [b][s][h*d]
    float* p0 = (float*)alloc((size_t)nX * 4);
    float* p1 = (float*)alloc((size_t)nX * 4);

    cvt_all_kernel<<<16384, 256, 0, stream>>>(query, key, value, Wq, Wk, Wv, Wo,
                                              xq, xk, xv, wqb, wkb, wvb, wob);

    qkv_gemm_kernel<<<dim3(32, 8, 3), 256, 0, stream>>>(
        xq, xk, xv, wqb, wkb, wvb, bq, bk, bv, qbuf, kbuf, vbuf);

    attn_kernel<<<1024, 256, 0, stream>>>(qbuf, kbuf, vbuf, attnb);

    oproj_kernel<<<dim3(32, 8, 2), 256, 0, stream>>>(attnb, wob, bo, query, p0, p1);

    ln_kernel<<<MM, 256, 0, stream>>>(p0, p1, ln_g, ln_b, out);
}

// Round 6
// 275.308 us; speedup vs baseline: 1.1707x; 1.0473x over previous
//
#include <hip/hip_runtime.h>
#include <hip/hip_bf16.h>

#define SQL 2048
#define SKL 2048
#define HH  1024
#define NHH 16
#define HDD 64
#define BB  2
#define MM  (BB*SQL)   // 4096 tokens

typedef __attribute__((ext_vector_type(8))) short short8;
typedef __attribute__((ext_vector_type(4))) short short4v;
typedef __attribute__((ext_vector_type(4))) float f32x4;
typedef unsigned short u16;

__device__ inline u16 f2bf(float f) {
    unsigned int u = __float_as_uint(f);
    u += 0x7fffu + ((u >> 16) & 1u);   // RNE
    return (u16)(u >> 16);
}

__device__ inline void gl_lds16(const void* g, void* l) {
    __builtin_amdgcn_global_load_lds(
        (const __attribute__((address_space(1))) unsigned int*)g,
        (__attribute__((address_space(3))) unsigned int*)l, 16, 0, 0);
}

// ---------------- fused fp32 -> bf16 convert (3 inputs + 4 weights, 1 launch) ----------------
__global__ __launch_bounds__(256) void cvt_all_kernel(
    const float* __restrict__ q, const float* __restrict__ k, const float* __restrict__ v,
    const float* __restrict__ wq, const float* __restrict__ wk,
    const float* __restrict__ wv, const float* __restrict__ wo,
    u16* __restrict__ xq, u16* __restrict__ xk, u16* __restrict__ xv,
    u16* __restrict__ wqb, u16* __restrict__ wkb, u16* __restrict__ wvb, u16* __restrict__ wob)
{
    int b = blockIdx.x;
    const float* src; u16* dst;
    if      (b < 4096)  { src = q;  dst = xq; }
    else if (b < 8192)  { src = k;  dst = xk;  b -= 4096; }
    else if (b < 12288) { src = v;  dst = xv;  b -= 8192; }
    else if (b < 13312) { src = wq; dst = wqb; b -= 12288; }
    else if (b < 14336) { src = wk; dst = wkb; b -= 13312; }
    else if (b < 15360) { src = wv; dst = wvb; b -= 14336; }
    else                { src = wo; dst = wob; b -= 15360; }
    int i = (b * 256 + threadIdx.x) * 4;
    float4 vv = *(const float4*)(src + i);
    ushort4 oo;
    oo.x = f2bf(vv.x); oo.y = f2bf(vv.y); oo.z = f2bf(vv.z); oo.w = f2bf(vv.w);
    *(ushort4*)(dst + i) = oo;
}

// ---------------- fused QKV projection GEMM (BK=64, async staging) ----------------
// A bf16 [4096][1024]; W bf16 [1024][1024]. 128x128 tile, BK=64.
// LDS tiles [128 rows][64 k] u16, xor-swizzle chunk ^ (row&7) -> conflict-free b128.
// z=0: Q -> [b][h][s][d] scaled 0.125*log2e; z=1: K -> [b][h][s][d];
// z=2: swapped MFMA operands -> V^T [b][h][d][s].
__global__ __launch_bounds__(256) void qkv_gemm_kernel(
    const u16* __restrict__ xq, const u16* __restrict__ xk, const u16* __restrict__ xv,
    const u16* __restrict__ wqb, const u16* __restrict__ wkb, const u16* __restrict__ wvb,
    const float* __restrict__ bq, const float* __restrict__ bk, const float* __restrict__ bv,
    u16* __restrict__ oq, u16* __restrict__ ok, u16* __restrict__ ov)
{
    const int z = blockIdx.z;
    const u16* A = (z == 0) ? xq : (z == 1) ? xk : xv;
    const u16* W = (z == 0) ? wqb : (z == 1) ? wkb : wvb;
    const float* bias = (z == 0) ? bq : (z == 1) ? bk : bv;
    u16* outb = (z == 0) ? oq : (z == 1) ? ok : ov;
    const float scale = (z == 0) ? 0.125f * 1.4426950408889634f : 1.0f;

    __shared__ u16 lds_a[128 * 64];
    __shared__ u16 lds_b[128 * 64];

    const int t = threadIdx.x;
    const int lane = t & 63;
    const int quad = lane >> 4;
    const int lo = lane & 15;
    const int wv_ = t >> 6;
    const int wm = (wv_ >> 1) * 64, wn = (wv_ & 1) * 64;
    const int m0 = blockIdx.x * 128;
    const int n0 = blockIdx.y * 128;

    f32x4 acc[4][4];
#pragma unroll
    for (int i = 0; i < 4; i++)
#pragma unroll
        for (int j = 0; j < 4; j++) acc[i][j] = (f32x4){0.f, 0.f, 0.f, 0.f};

    // staging: 4 slots/thread/tile; slot s: row s>>3, holds global chunk (s&7)^(row&7)
    int srow[4], scol[4];
#pragma unroll
    for (int i = 0; i < 4; i++) {
        int s = t + i * 256;
        srow[i] = s >> 3;
        scol[i] = ((s & 7) ^ (srow[i] & 7)) * 8;
    }

    for (int k0 = 0; k0 < HH; k0 += 64) {
#pragma unroll
        for (int i = 0; i < 4; i++) {
            int s = t + i * 256;
            gl_lds16(A + (size_t)(m0 + srow[i]) * HH + k0 + scol[i], &lds_a[s * 8]);
            gl_lds16(W + (size_t)(n0 + srow[i]) * HH + k0 + scol[i], &lds_b[s * 8]);
        }
        __syncthreads();
#pragma unroll
        for (int kh = 0; kh < 2; kh++) {
            short8 af[4], bf[4];
#pragma unroll
            for (int i = 0; i < 4; i++) {
                const int ra = wm + i * 16 + lo;
                const int rb = wn + i * 16 + lo;
                const int ca = (((kh << 2) | quad) ^ (ra & 7)) * 8;
                const int cb = (((kh << 2) | quad) ^ (rb & 7)) * 8;
                af[i] = *(const short8*)&lds_a[ra * 64 + ca];
                bf[i] = *(const short8*)&lds_b[rb * 64 + cb];
            }
            if (z == 2) {
#pragma unroll
                for (int i = 0; i < 4; i++)
#pragma unroll
                    for (int j = 0; j < 4; j++)
                        acc[i][j] = __builtin_amdgcn_mfma_f32_16x16x32_bf16(bf[j], af[i], acc[i][j], 0, 0, 0);
            } else {
#pragma unroll
                for (int i = 0; i < 4; i++)
#pragma unroll
                    for (int j = 0; j < 4; j++)
                        acc[i][j] = __builtin_amdgcn_mfma_f32_16x16x32_bf16(af[i], bf[j], acc[i][j], 0, 0, 0);
            }
        }
        __syncthreads();
    }

#pragma unroll
    for (int i = 0; i < 4; i++) {
#pragma unroll
        for (int j = 0; j < 4; j++) {
#pragma unroll
            for (int r = 0; r < 4; r++) {
                if (z == 2) {
                    int dg  = n0 + wn + j * 16 + quad * 4 + r;   // weight dim
                    int tok = m0 + wm + i * 16 + lo;
                    float val = acc[i][j][r] + bias[dg];
                    int head = dg >> 6, d = dg & 63;
                    int bi = tok >> 11, s = tok & 2047;
                    outb[(((size_t)bi * NHH + head) * HDD + d) * SKL + s] = f2bf(val);
                } else {
                    int row = m0 + wm + i * 16 + quad * 4 + r;   // token
                    int col = n0 + wn + j * 16 + lo;
                    float val = (acc[i][j][r] + bias[col]) * scale;
                    int bi = row >> 11, s = row & 2047;
                    int head = col >> 6, d = col & 63;
                    outb[(((size_t)bi * NHH + head) * SQL + s) * HDD + d] = f2bf(val);
                }
            }
        }
    }
}

// ---------------- out-projection GEMM, split-K=2, BK=64 ----------------
__global__ __launch_bounds__(256) void oproj_kernel(
    const u16* __restrict__ A, const u16* __restrict__ W,
    const float* __restrict__ bias, const float* __restrict__ resid,
    float* __restrict__ p0, float* __restrict__ p1)
{
    const int z = blockIdx.z;
    float* outf = z ? p1 : p0;

    __shared__ u16 lds_a[128 * 64];
    __shared__ u16 lds_b[128 * 64];

    const int t = threadIdx.x;
    const int lane = t & 63;
    const int quad = lane >> 4;
    const int lo = lane & 15;
    const int wv_ = t >> 6;
    const int wm = (wv_ >> 1) * 64, wn = (wv_ & 1) * 64;
    const int m0 = blockIdx.x * 128;
    const int n0 = blockIdx.y * 128;

    f32x4 acc[4][4];
#pragma unroll
    for (int i = 0; i < 4; i++)
#pragma unroll
        for (int j = 0; j < 4; j++) acc[i][j] = (f32x4){0.f, 0.f, 0.f, 0.f};

    int srow[4], scol[4];
#pragma unroll
    for (int i = 0; i < 4; i++) {
        int s = t + i * 256;
        srow[i] = s >> 3;
        scol[i] = ((s & 7) ^ (srow[i] & 7)) * 8;
    }

    const int kbeg = z * 512, kend = kbeg + 512;
    for (int k0 = kbeg; k0 < kend; k0 += 64) {
#pragma unroll
        for (int i = 0; i < 4; i++) {
            int s = t + i * 256;
            gl_lds16(A + (size_t)(m0 + srow[i]) * HH + k0 + scol[i], &lds_a[s * 8]);
            gl_lds16(W + (size_t)(n0 + srow[i]) * HH + k0 + scol[i], &lds_b[s * 8]);
        }
        __syncthreads();
#pragma unroll
        for (int kh = 0; kh < 2; kh++) {
            short8 af[4], bf[4];
#pragma unroll
            for (int i = 0; i < 4; i++) {
                const int ra = wm + i * 16 + lo;
                const int rb = wn + i * 16 + lo;
                const int ca = (((kh << 2) | quad) ^ (ra & 7)) * 8;
                const int cb = (((kh << 2) | quad) ^ (rb & 7)) * 8;
                af[i] = *(const short8*)&lds_a[ra * 64 + ca];
                bf[i] = *(const short8*)&lds_b[rb * 64 + cb];
            }
#pragma unroll
            for (int i = 0; i < 4; i++)
#pragma unroll
                for (int j = 0; j < 4; j++)
                    acc[i][j] = __builtin_amdgcn_mfma_f32_16x16x32_bf16(af[i], bf[j], acc[i][j], 0, 0, 0);
        }
        __syncthreads();
    }

#pragma unroll
    for (int i = 0; i < 4; i++) {
#pragma unroll
        for (int j = 0; j < 4; j++) {
#pragma unroll
            for (int r = 0; r < 4; r++) {
                int row = m0 + wm + i * 16 + quad * 4 + r;
                int col = n0 + wn + j * 16 + lo;
                float val = acc[i][j][r];
                if (z == 0) val += bias[col] + resid[(size_t)row * HH + col];
                outf[(size_t)row * HH + col] = val;
            }
        }
    }
}

// ---------------- Flash attention (R2-verbatim: 64-key tiles, S^T orientation) ----------------
#define PSTR 72   // [16 q][64 key] P tile row stride (u16)

__global__ __launch_bounds__(256) void attn_kernel(
    const u16* __restrict__ qb, const u16* __restrict__ kb, const u16* __restrict__ vtb,
    u16* __restrict__ attn_out)
{
    __shared__ u16 k_lds[64 * 64];
    __shared__ u16 vt_lds[64 * 64];
    __shared__ u16 p_lds[4 * 16 * PSTR];

    const int t = threadIdx.x;
    const int lane = t & 63;
    const int quad = lane >> 4;
    const int lo = lane & 15;
    const int w = t >> 6;
    const int qt = (SQL / 64 - 1) - (blockIdx.x >> 5);  // heavy q-tiles first
    const int bh = blockIdx.x & 31;
    const int q0 = qt * 64;

    const u16* qbase = qb + ((size_t)bh * SQL + q0 + w * 16 + lo) * HDD + quad * 8;
    short8 qf0 = *(const short8*)qbase;
    short8 qf1 = *(const short8*)(qbase + 32);

    float m_s = -__builtin_inff(), l_s = 0.f;   // per q = lane&15 (replicated per quad)
    f32x4 o[4];
#pragma unroll
    for (int j = 0; j < 4; j++) o[j] = (f32x4){0.f, 0.f, 0.f, 0.f};

    const int sl0 = t, sl1 = 256 + t;
    const int r0 = sl0 >> 3, c0 = ((sl0 & 7) ^ (r0 & 7)) * 8;
    const int r1 = sl1 >> 3, c1 = ((sl1 & 7) ^ (r1 & 7)) * 8;
    const u16* kbh = kb + (size_t)bh * SKL * HDD;
    const u16* vbh = vtb + (size_t)bh * HDD * SKL;
    u16* ppriv = &p_lds[w * 16 * PSTR];

    for (int kt = 0; kt <= qt; kt++) {
        const int k0 = kt * 64;
        gl_lds16(kbh + (size_t)(k0 + r0) * HDD + c0, &k_lds[sl0 * 8]);
        gl_lds16(kbh + (size_t)(k0 + r1) * HDD + c1, &k_lds[sl1 * 8]);
        gl_lds16(vbh + (size_t)r0 * SKL + k0 + c0, &vt_lds[sl0 * 8]);
        gl_lds16(vbh + (size_t)r1 * SKL + k0 + c1, &vt_lds[sl1 * 8]);
        __syncthreads();

        // S^T = K·Q^T
        f32x4 s[4];
#pragma unroll
        for (int nt = 0; nt < 4; nt++) {
            const int row = nt * 16 + lo;
            short8 kf0 = *(const short8*)&k_lds[row * 64 + ((quad ^ (row & 7)) * 8)];
            short8 kf1 = *(const short8*)&k_lds[row * 64 + (((4 + quad) ^ (row & 7)) * 8)];
            s[nt] = (f32x4){0.f, 0.f, 0.f, 0.f};
            s[nt] = __builtin_amdgcn_mfma_f32_16x16x32_bf16(kf0, qf0, s[nt], 0, 0, 0);
            s[nt] = __builtin_amdgcn_mfma_f32_16x16x32_bf16(kf1, qf1, s[nt], 0, 0, 0);
        }
        if (kt == qt) {   // diagonal tile: mask key > q
            const int ql = w * 16 + lo;
#pragma unroll
            for (int nt = 0; nt < 4; nt++)
#pragma unroll
                for (int r = 0; r < 4; r++)
                    if (nt * 16 + quad * 4 + r > ql) s[nt][r] = -__builtin_inff();
        }

        // online softmax (log2 domain)
        float mx = s[0][0];
#pragma unroll
        for (int nt = 0; nt < 4; nt++)
#pragma unroll
            for (int r = 0; r < 4; r++) mx = fmaxf(mx, s[nt][r]);
        mx = fmaxf(mx, __shfl_xor(mx, 16));
        mx = fmaxf(mx, __shfl_xor(mx, 32));
        float mnew = fmaxf(m_s, mx);
        float al = __builtin_amdgcn_exp2f(m_s - mnew);
        m_s = mnew;
        float rs = 0.f;
#pragma unroll
        for (int nt = 0; nt < 4; nt++)
#pragma unroll
            for (int r = 0; r < 4; r++) {
                s[nt][r] = __builtin_amdgcn_exp2f(s[nt][r] - m_s);
                rs += s[nt][r];
            }
        rs += __shfl_xor(rs, 16);
        rs += __shfl_xor(rs, 32);
        l_s = l_s * al + rs;

        float alr[4];
#pragma unroll
        for (int r = 0; r < 4; r++) alr[r] = __shfl(al, quad * 4 + r, 16);
#pragma unroll
        for (int nt = 0; nt < 4; nt++)
#pragma unroll
            for (int r = 0; r < 4; r++) o[nt][r] *= alr[r];

        // P store: 4 consecutive keys per lane, b64 writes
#pragma unroll
        for (int nt = 0; nt < 4; nt++) {
            short4v pk;
#pragma unroll
            for (int r = 0; r < 4; r++) pk[r] = (short)f2bf(s[nt][r]);
            *(short4v*)&ppriv[lo * PSTR + nt * 16 + quad * 4] = pk;
        }
        short8 pf0 = *(const short8*)&ppriv[lo * PSTR + quad * 8];
        short8 pf1 = *(const short8*)&ppriv[lo * PSTR + 32 + quad * 8];

        // O += P·V
#pragma unroll
        for (int nt = 0; nt < 4; nt++) {
            const int row = nt * 16 + lo;
            short8 vf0 = *(const short8*)&vt_lds[row * 64 + ((quad ^ (row & 7)) * 8)];
            short8 vf1 = *(const short8*)&vt_lds[row * 64 + (((4 + quad) ^ (row & 7)) * 8)];
            o[nt] = __builtin_amdgcn_mfma_f32_16x16x32_bf16(pf0, vf0, o[nt], 0, 0, 0);
            o[nt] = __builtin_amdgcn_mfma_f32_16x16x32_bf16(pf1, vf1, o[nt], 0, 0, 0);
        }
        __syncthreads();
    }

    // epilogue
    const int b = bh >> 4, h = bh & 15;
    float inv[4];
#pragma unroll
    for (int r = 0; r < 4; r++) inv[r] = 1.0f / __shfl(l_s, quad * 4 + r, 16);
#pragma unroll
    for (int nt = 0; nt < 4; nt++)
#pragma unroll
        for (int r = 0; r < 4; r++) {
            int srow = q0 + w * 16 + quad * 4 + r;
            attn_out[((size_t)b * SQL + srow) * HH + h * HDD + nt * 16 + lo] =
                f2bf(o[nt][r] * inv[r]);
        }
}

// ---------------- LayerNorm over split-K partials ----------------
__global__ __launch_bounds__(256) void ln_kernel(const float* __restrict__ p0,
                                                 const float* __restrict__ p1,
                                                 const float* __restrict__ g,
                                                 const float* __restrict__ bb,
                                                 float* __restrict__ out)
{
    const int row = blockIdx.x;
    const int t = threadIdx.x;
    float4 a = *(const float4*)(p0 + (size_t)row * HH + t * 4);
    float4 c = *(const float4*)(p1 + (size_t)row * HH + t * 4);
    float4 v;
    v.x = a.x + c.x; v.y = a.y + c.y; v.z = a.z + c.z; v.w = a.w + c.w;
    float s1 = v.x + v.y + v.z + v.w;
    float s2 = v.x * v.x + v.y * v.y + v.z * v.z + v.w * v.w;
#pragma unroll
    for (int off = 32; off; off >>= 1) { s1 += __shfl_xor(s1, off); s2 += __shfl_xor(s2, off); }
    __shared__ float red[8];
    if ((t & 63) == 0) { red[(t >> 6) * 2] = s1; red[(t >> 6) * 2 + 1] = s2; }
    __syncthreads();
    s1 = red[0] + red[2] + red[4] + red[6];
    s2 = red[1] + red[3] + red[5] + red[7];
    float mu = s1 * (1.0f / HH);
    float var = s2 * (1.0f / HH) - mu * mu;
    float rstd = rsqrtf(var + 1e-5f);
    float4 gg = *(const float4*)(g + t * 4);
    float4 b4 = *(const float4*)(bb + t * 4);
    float4 o;
    o.x = (v.x - mu) * rstd * gg.x + b4.x;
    o.y = (v.y - mu) * rstd * gg.y + b4.y;
    o.z = (v.z - mu) * rstd * gg.z + b4.z;
    o.w = (v.w - mu) * rstd * gg.w + b4.w;
    *(float4*)(out + (size_t)row * HH + t * 4) = o;
}

extern "C" void kernel_launch(void* const* d_in, const int* in_sizes, int n_in,
                              void* d_out, int out_size, void* d_ws, size_t ws_size,
                              hipStream_t stream)
{
    const float* query = (const float*)d_in[0];
    const float* key   = (const float*)d_in[1];
    const float* value = (const float*)d_in[2];
    // d_in[3] = causal_mask (tril by construction; causality hardcoded)
    const float* Wq = (const float*)d_in[4];
    const float* bq = (const float*)d_in[5];
    const float* Wk = (const float*)d_in[6];
    const float* bk = (const float*)d_in[7];
    const float* Wv = (const float*)d_in[8];
    const float* bv = (const float*)d_in[9];
    const float* Wo = (const float*)d_in[10];
    const float* bo = (const float*)d_in[11];
    const float* ln_g = (const float*)d_in[12];
    const float* ln_b = (const float*)d_in[13];
    float* out = (float*)d_out;

    char* wp = (char*)d_ws;
    auto alloc = [&](size_t bytes) { void* p = (void*)wp; wp += (bytes + 255) & ~(size_t)255; return p; };
    const int nW = HH * HH;    // 1M
    const int nX = MM * HH;    // 4M
    u16* wqb = (u16*)alloc((size_t)nW * 2);
    u16* wkb = (u16*)alloc((size_t)nW * 2);
    u16* wvb = (u16*)alloc((size_t)nW * 2);
    u16* wob = (u16*)alloc((size_t)nW * 2);
    u16* xq  = (u16*)alloc((size_t)nX * 2);
    u16* xk  = (u16*)alloc((size_t)nX * 2);
    u16* xv  = (u16*)alloc((size_t)nX * 2);
    u16* qbuf = (u16*)alloc((size_t)nX * 2);   // [b][h][s][d]
    u16* kbuf = (u16*)alloc((size_t)nX * 2);   // [b][h][s][d]
    u16* vbuf = (u16*)alloc((size_t)nX * 2);   // V^T [b][h][d][s]
    u16* attnb = (u16*)alloc((size_t)nX * 2);  // [b][s][h*d]
    float* p0 = (float*)alloc((size_t)nX * 4);
    float* p1 = (float*)alloc((size_t)nX * 4);

    cvt_all_kernel<<<16384, 256, 0, stream>>>(query, key, value, Wq, Wk, Wv, Wo,
                                              xq, xk, xv, wqb, wkb, wvb, wob);

    qkv_gemm_kernel<<<dim3(32, 8, 3), 256, 0, stream>>>(
        xq, xk, xv, wqb, wkb, wvb, bq, bk, bv, qbuf, kbuf, vbuf);

    attn_kernel<<<1024, 256, 0, stream>>>(qbuf, kbuf, vbuf, attnb);

    oproj_kernel<<<dim3(32, 8, 2), 256, 0, stream>>>(attnb, wob, bo, query, p0, p1);

    ln_kernel<<<MM, 256, 0, stream>>>(p0, p1, ln_g, ln_b, out);
}